// Round 1
// baseline (2694.994 us; speedup 1.0000x reference)
//
#include <hip/hip_runtime.h>
#include <math.h>

#define NN 100000
#define EE 1600000
#define NFEATC 512
#define NHIDC 256
#define NCC 64
#define ALPHA_C 0.1f
#define NSLOPE_C 0.2f

// ---------------- GEMM: C = act(A@B + bias), tile 64x64, KT=16, 256 thr, 4x4 micro ----------------
template<int ACT>  // 0 = none, 1 = elu
__global__ __launch_bounds__(256)
void gemm_kernel(const float* __restrict__ A, const float* __restrict__ B,
                 const float* __restrict__ bias, float* __restrict__ C,
                 int M, int K, int Ncols)
{
    __shared__ float As[16][68];   // k-major, padded (16B-aligned rows, broken pow2 stride)
    __shared__ float Bs[16][64];
    const int tid = threadIdx.x;
    const int bm = blockIdx.x * 64;
    const int bn = blockIdx.y * 64;
    const int m0 = (tid & 15) * 4;
    const int n0 = (tid >> 4) * 4;
    float acc[4][4] = {};

    const int am = bm + (tid >> 2);       // A stage: row
    const int ak = (tid & 3) * 4;         // A stage: k offset (float4)
    const int bk = tid >> 4;              // B stage: k row
    const int bn4 = bn + (tid & 15) * 4;  // B stage: col (float4)

    for (int kt = 0; kt < K; kt += 16) {
        float4 av;
        if (am < M) av = *reinterpret_cast<const float4*>(A + (size_t)am * K + kt + ak);
        else        av = make_float4(0.f, 0.f, 0.f, 0.f);
        float4 bv = *reinterpret_cast<const float4*>(B + (size_t)(kt + bk) * Ncols + bn4);
        __syncthreads();
        As[ak + 0][tid >> 2] = av.x;
        As[ak + 1][tid >> 2] = av.y;
        As[ak + 2][tid >> 2] = av.z;
        As[ak + 3][tid >> 2] = av.w;
        *reinterpret_cast<float4*>(&Bs[bk][(tid & 15) * 4]) = bv;
        __syncthreads();
        #pragma unroll
        for (int k = 0; k < 16; ++k) {
            float4 a4 = *reinterpret_cast<const float4*>(&As[k][m0]);
            float4 b4 = *reinterpret_cast<const float4*>(&Bs[k][n0]);
            float a_[4] = {a4.x, a4.y, a4.z, a4.w};
            float b_[4] = {b4.x, b4.y, b4.z, b4.w};
            #pragma unroll
            for (int i = 0; i < 4; ++i)
                #pragma unroll
                for (int j = 0; j < 4; ++j)
                    acc[i][j] = fmaf(a_[i], b_[j], acc[i][j]);
        }
    }

    float bvals[4] = {0.f, 0.f, 0.f, 0.f};
    if (bias) {
        bvals[0] = bias[bn + n0 + 0]; bvals[1] = bias[bn + n0 + 1];
        bvals[2] = bias[bn + n0 + 2]; bvals[3] = bias[bn + n0 + 3];
    }
    #pragma unroll
    for (int i = 0; i < 4; ++i) {
        int r = bm + m0 + i;
        if (r >= M) break;
        float v[4];
        #pragma unroll
        for (int j = 0; j < 4; ++j) {
            float t = acc[i][j] + bvals[j];
            if (ACT == 1) t = (t > 0.f) ? t : (expf(t) - 1.f);
            v[j] = t;
        }
        float4 o = make_float4(v[0], v[1], v[2], v[3]);
        *reinterpret_cast<float4*>(C + (size_t)r * Ncols + bn + n0) = o;
    }
}

// ---------------- per-node attention scalars: el, er ----------------
__global__ __launch_bounds__(256)
void attn_kernel(const float* __restrict__ h, const float* __restrict__ attn_l,
                 const float* __restrict__ attn_r, float* __restrict__ el, float* __restrict__ er)
{
    int node = blockIdx.x * 4 + (threadIdx.x >> 6);
    int lane = threadIdx.x & 63;
    if (node >= NN) return;
    float v = h[(size_t)node * 64 + lane];
    float lr = (v > 0.f) ? v : NSLOPE_C * v;
    float a = lr * attn_l[lane];
    float b = lr * attn_r[lane];
    #pragma unroll
    for (int m = 1; m < 64; m <<= 1) {
        a += __shfl_xor(a, m);
        b += __shfl_xor(b, m);
    }
    if (lane == 0) { el[node] = a; er[node] = b; }
}

// ---------------- edge kernel: ew, deg sums, lp partials ----------------
__global__ __launch_bounds__(256)
void edge_kernel(const int* __restrict__ src, const int* __restrict__ dst,
                 const float* __restrict__ wts,
                 const float* __restrict__ h, const float* __restrict__ hl,
                 const float* __restrict__ el, const float* __restrict__ er,
                 const float* __restrict__ s_attn, const float* __restrict__ beta,
                 const float* __restrict__ aw,
                 float* __restrict__ ew, float* __restrict__ deg_s, float* __restrict__ deg_d,
                 float* __restrict__ lp_part)
{
    int tid = blockIdx.x * 256 + threadIdx.x;
    int e = tid >> 4;            // 16 lanes per edge
    int j = threadIdx.x & 15;
    float lp_p = 0.f, se_p = 0.f, sdf_p = 0.f, sds_p = 0.f;
    int s = 0, d = 0;
    if (e < EE) {
        s = src[e]; d = dst[e];
        const float4 hs = *reinterpret_cast<const float4*>(h  + (size_t)s * 64 + j * 4);
        const float4 hd = *reinterpret_cast<const float4*>(h  + (size_t)d * 64 + j * 4);
        const float4 ls = *reinterpret_cast<const float4*>(hl + (size_t)s * 64 + j * 4);
        const float4 ld = *reinterpret_cast<const float4*>(hl + (size_t)d * 64 + j * 4);
        const float4 sa = *reinterpret_cast<const float4*>(s_attn + j * 4);
        se_p = ls.x * sa.x * ld.x + ls.y * sa.y * ld.y + ls.z * sa.z * ld.z + ls.w * sa.w * ld.w;
        float dx = hs.x - hd.x, dy = hs.y - hd.y, dz = hs.z - hd.z, dw = hs.w - hd.w;
        sdf_p = dx * dx + dy * dy + dz * dz + dw * dw;
        float ex = ls.x - ld.x, ey = ls.y - ld.y, ez = ls.z - ld.z, ec = ls.w - ld.w;
        sds_p = ex * ex + ey * ey + ez * ez + ec * ec;
        float dot = ls.x * ld.x + ls.y * ld.y + ls.z * ld.z + ls.w * ld.w;
        lp_p = dot * wts[e];
    }
    #pragma unroll
    for (int m = 1; m < 16; m <<= 1) {
        se_p  += __shfl_xor(se_p, m);
        sdf_p += __shfl_xor(sdf_p, m);
        sds_p += __shfl_xor(sds_p, m);
    }
    if (e < EE && j == 0) {
        float betaw = 2.f / (expf(-beta[0]) + 1.f);
        float a0 = aw[0], a1 = aw[1];
        float mx = fmaxf(a0, a1);
        float e0 = expf(a0 - mx), e1 = expf(a1 - mx);
        float inv = 1.f / (e0 + e1);
        float w0 = e0 * inv, w1 = e1 * inv;
        float evv = el[s] + er[d] + se_p;
        float dd = w0 * sdf_p + w1 * sds_p;
        float v = expf(evv - betaw * dd) + 1e-9f;
        ew[e] = v;
        atomicAdd(deg_s + s, v);
        atomicAdd(deg_d + d, v);
    }
    // lp: full-wave reduce of per-lane partials (4 edges per wave)
    #pragma unroll
    for (int m = 1; m < 64; m <<= 1) lp_p += __shfl_xor(lp_p, m);
    __shared__ float lred[4];
    if ((threadIdx.x & 63) == 0) lred[threadIdx.x >> 6] = lp_p;
    __syncthreads();
    if (threadIdx.x == 0) lp_part[blockIdx.x] = lred[0] + lred[1] + lred[2] + lred[3];
}

// ---------------- reduce lp partials ----------------
__global__ __launch_bounds__(256)
void reduce_kernel(const float* __restrict__ part, int n, float* __restrict__ out)
{
    float s = 0.f;
    for (int i = threadIdx.x; i < n; i += 256) s += part[i];
    #pragma unroll
    for (int m = 1; m < 64; m <<= 1) s += __shfl_xor(s, m);
    __shared__ float sd[4];
    if ((threadIdx.x & 63) == 0) sd[threadIdx.x >> 6] = s;
    __syncthreads();
    if (threadIdx.x == 0) out[0] = sd[0] + sd[1] + sd[2] + sd[3];
}

// ---------------- edge normalization ----------------
__global__ __launch_bounds__(256)
void wnorm_kernel(const int* __restrict__ src, const int* __restrict__ dst,
                  const float* __restrict__ deg_s, const float* __restrict__ deg_d,
                  const float* __restrict__ theta, float* __restrict__ ew)
{
    int e = blockIdx.x * 256 + threadIdx.x;
    if (e >= EE) return;
    float perm = 1e-9f / (expf(-theta[0]) + 1.f);
    float v = ew[e] * rsqrtf(deg_s[src[e]]) * rsqrtf(deg_d[dst[e]]) + perm;
    ew[e] = v;
}

// ---------------- CSR build ----------------
__global__ __launch_bounds__(256)
void count_kernel(const int* __restrict__ dst, int* __restrict__ cnt)
{
    int e = blockIdx.x * 256 + threadIdx.x;
    if (e < EE) atomicAdd(cnt + dst[e], 1);
}

__global__ __launch_bounds__(1024)
void scan_kernel(const int* __restrict__ cnt, int* __restrict__ row, int* __restrict__ cur)
{
    __shared__ int sums[1024];
    int t = threadIdx.x;
    const int CH = (NN + 1023) / 1024;
    int lo = t * CH, hi = min(lo + CH, NN);
    int s = 0;
    for (int i = lo; i < hi; ++i) s += cnt[i];
    sums[t] = s;
    __syncthreads();
    for (int off = 1; off < 1024; off <<= 1) {
        int add = (t >= off) ? sums[t - off] : 0;
        __syncthreads();
        sums[t] += add;
        __syncthreads();
    }
    int running = sums[t] - s;  // exclusive base
    for (int i = lo; i < hi; ++i) {
        row[i] = running;
        cur[i] = running;
        running += cnt[i];
    }
    if (t == 1023) row[NN] = sums[1023];
}

__global__ __launch_bounds__(256)
void bucket_kernel(const int* __restrict__ src, const int* __restrict__ dst,
                   const float* __restrict__ w, int* __restrict__ cur,
                   int* __restrict__ csr_src, float* __restrict__ csr_w)
{
    int e = blockIdx.x * 256 + threadIdx.x;
    if (e >= EE) return;
    int d = dst[e];
    int pos = atomicAdd(cur + d, 1);
    csr_src[pos] = src[e];
    csr_w[pos] = (1.0f - ALPHA_C) * w[e];
}

// ---------------- propagation: fout = 0.9*sum(w*fin[src]) + 0.1*h (0.9 folded into csr_w) -----
__global__ __launch_bounds__(256)
void prop_kernel(const float* __restrict__ fin, const float* __restrict__ h,
                 const int* __restrict__ row, const int* __restrict__ csr_src,
                 const float* __restrict__ csr_w, float* __restrict__ fout)
{
    int node = blockIdx.x * 4 + (threadIdx.x >> 6);
    int lane = threadIdx.x & 63;
    if (node >= NN) return;
    float acc = ALPHA_C * h[(size_t)node * 64 + lane];
    int b = row[node], en = row[node + 1];
    for (int e = b; e < en; ++e) {
        int s = csr_src[e];
        float wv = csr_w[e];
        acc += wv * fin[(size_t)s * 64 + lane];
    }
    fout[(size_t)node * 64 + lane] = acc;
}

// ---------------- epilogue: out = log_softmax(elu(fp)) ----------------
__global__ __launch_bounds__(256)
void out_kernel(const float* __restrict__ fp, float* __restrict__ out)
{
    int node = blockIdx.x * 4 + (threadIdx.x >> 6);
    int lane = threadIdx.x & 63;
    if (node >= NN) return;
    float v = fp[(size_t)node * 64 + lane];
    float ev = (v > 0.f) ? v : (expf(v) - 1.f);
    float m = ev;
    #pragma unroll
    for (int k = 1; k < 64; k <<= 1) m = fmaxf(m, __shfl_xor(m, k));
    float s = expf(ev - m);
    #pragma unroll
    for (int k = 1; k < 64; k <<= 1) s += __shfl_xor(s, k);
    out[(size_t)node * 64 + lane] = ev - m - logf(s);
}

extern "C" void kernel_launch(void* const* d_in, const int* in_sizes, int n_in,
                              void* d_out, int out_size, void* d_ws, size_t ws_size,
                              hipStream_t stream)
{
    const float* x      = (const float*)d_in[0];
    const int*   src    = (const int*)d_in[1];
    const int*   dst    = (const int*)d_in[2];
    const float* wts    = (const float*)d_in[3];
    const float* latp   = (const float*)d_in[4];
    const float* W_in   = (const float*)d_in[5];
    const float* W_out  = (const float*)d_in[6];
    const float* Ws1    = (const float*)d_in[7];
    const float* b1     = (const float*)d_in[8];
    const float* Ws2    = (const float*)d_in[9];
    const float* b2     = (const float*)d_in[10];
    const float* attn_l = (const float*)d_in[11];
    const float* attn_r = (const float*)d_in[12];
    const float* s_attn = (const float*)d_in[13];
    const float* beta   = (const float*)d_in[14];
    const float* theta  = (const float*)d_in[15];
    const float* aw     = (const float*)d_in[16];

    float* out = (float*)d_out;
    float* lp  = out + (size_t)NN * 64;

    char* w8 = (char*)d_ws;
    size_t off = 0;
    auto alloc = [&](size_t bytes) -> char* {
        char* p = w8 + off;
        off += (bytes + 255) / 256 * 256;
        return p;
    };
    // big region: h1 (NN x 256) lives only between gemm1 and gemm2; afterwards
    // reused for hl_tmp (first 64 cols) and fpA/fpB ping-pong buffers.
    float* big    = (float*)alloc((size_t)NN * 256 * 4);
    float* h1     = big;
    float* hl_tmp = big;
    float* fpA    = big;
    float* fpB    = big + (size_t)NN * 64;
    float* h      = (float*)alloc((size_t)NN * 64 * 4);
    float* hl     = (float*)alloc((size_t)NN * 64 * 4);
    float* ew     = (float*)alloc((size_t)EE * 4);
    float* el     = (float*)alloc((size_t)NN * 4);
    float* er     = (float*)alloc((size_t)NN * 4);
    float* deg_s  = (float*)alloc((size_t)NN * 4);
    float* deg_d  = (float*)alloc((size_t)NN * 4);
    int*   cnt    = (int*)alloc((size_t)NN * 4);
    int*   row    = (int*)alloc((size_t)(NN + 1) * 4);
    int*   cur    = (int*)alloc((size_t)NN * 4);
    int*   csr_src= (int*)alloc((size_t)EE * 4);
    float* csr_w  = (float*)alloc((size_t)EE * 4);
    float* lp_part= (float*)alloc((size_t)100000 * 4);

    hipMemsetAsync(cnt,   0, (size_t)NN * 4, stream);
    hipMemsetAsync(deg_s, 0, (size_t)NN * 4, stream);
    hipMemsetAsync(deg_d, 0, (size_t)NN * 4, stream);

    const int MB = (NN + 63) / 64;  // 1563
    // h1 = elu(x @ W_in)
    gemm_kernel<1><<<dim3(MB, NHIDC / 64), 256, 0, stream>>>(x, W_in, nullptr, h1, NN, NFEATC, NHIDC);
    // h = h1 @ W_out
    gemm_kernel<0><<<dim3(MB, 1), 256, 0, stream>>>(h1, W_out, nullptr, h, NN, NHIDC, NCC);
    // hl = elu(elu(latp@Ws1+b1)@Ws2+b2)
    gemm_kernel<1><<<dim3(MB, 1), 256, 0, stream>>>(latp, Ws1, b1, hl_tmp, NN, NCC, NCC);
    gemm_kernel<1><<<dim3(MB, 1), 256, 0, stream>>>(hl_tmp, Ws2, b2, hl, NN, NCC, NCC);

    attn_kernel<<<NN / 4, 256, 0, stream>>>(h, attn_l, attn_r, el, er);
    count_kernel<<<EE / 256, 256, 0, stream>>>(dst, cnt);
    scan_kernel<<<1, 1024, 0, stream>>>(cnt, row, cur);

    edge_kernel<<<EE * 16 / 256, 256, 0, stream>>>(src, dst, wts, h, hl, el, er,
                                                   s_attn, beta, aw, ew, deg_s, deg_d, lp_part);
    reduce_kernel<<<1, 256, 0, stream>>>(lp_part, EE * 16 / 256 > 100000 ? 100000 : EE * 16 / 256, lp);

    wnorm_kernel<<<EE / 256, 256, 0, stream>>>(src, dst, deg_s, deg_d, theta, ew);
    bucket_kernel<<<EE / 256, 256, 0, stream>>>(src, dst, ew, cur, csr_src, csr_w);

    const float* fin = h;
    float* bufs[2] = {fpA, fpB};
    for (int it = 0; it < 8; ++it) {
        float* fo = bufs[it & 1];
        prop_kernel<<<NN / 4, 256, 0, stream>>>(fin, h, row, csr_src, csr_w, fo);
        fin = fo;
    }
    out_kernel<<<NN / 4, 256, 0, stream>>>(fin, out);
}

// Round 2
// 2021.667 us; speedup vs baseline: 1.3331x; 1.3331x over previous
//
#include <hip/hip_runtime.h>
#include <math.h>

#define NN 100000
#define EE 1600000
#define NFEATC 512
#define NHIDC 256
#define NCC 64
#define ALPHA_C 0.1f
#define NSLOPE_C 0.2f

// ---------------- GEMM: C = act(A@B + bias), tile 64x64, KT=16, 256 thr, 4x4 micro ----------------
template<int ACT>  // 0 = none, 1 = elu
__global__ __launch_bounds__(256)
void gemm_kernel(const float* __restrict__ A, const float* __restrict__ B,
                 const float* __restrict__ bias, float* __restrict__ C,
                 int M, int K, int Ncols)
{
    __shared__ float As[16][68];   // k-major, padded
    __shared__ float Bs[16][64];
    const int tid = threadIdx.x;
    const int bm = blockIdx.x * 64;
    const int bn = blockIdx.y * 64;
    const int m0 = (tid & 15) * 4;
    const int n0 = (tid >> 4) * 4;
    float acc[4][4] = {};

    const int am = bm + (tid >> 2);       // A stage: row
    const int ak = (tid & 3) * 4;         // A stage: k offset (float4)
    const int bk = tid >> 4;              // B stage: k row
    const int bn4 = bn + (tid & 15) * 4;  // B stage: col (float4)

    for (int kt = 0; kt < K; kt += 16) {
        float4 av;
        if (am < M) av = *reinterpret_cast<const float4*>(A + (size_t)am * K + kt + ak);
        else        av = make_float4(0.f, 0.f, 0.f, 0.f);
        float4 bv = *reinterpret_cast<const float4*>(B + (size_t)(kt + bk) * Ncols + bn4);
        __syncthreads();
        As[ak + 0][tid >> 2] = av.x;
        As[ak + 1][tid >> 2] = av.y;
        As[ak + 2][tid >> 2] = av.z;
        As[ak + 3][tid >> 2] = av.w;
        *reinterpret_cast<float4*>(&Bs[bk][(tid & 15) * 4]) = bv;
        __syncthreads();
        #pragma unroll
        for (int k = 0; k < 16; ++k) {
            float4 a4 = *reinterpret_cast<const float4*>(&As[k][m0]);
            float4 b4 = *reinterpret_cast<const float4*>(&Bs[k][n0]);
            float a_[4] = {a4.x, a4.y, a4.z, a4.w};
            float b_[4] = {b4.x, b4.y, b4.z, b4.w};
            #pragma unroll
            for (int i = 0; i < 4; ++i)
                #pragma unroll
                for (int j = 0; j < 4; ++j)
                    acc[i][j] = fmaf(a_[i], b_[j], acc[i][j]);
        }
    }

    float bvals[4] = {0.f, 0.f, 0.f, 0.f};
    if (bias) {
        bvals[0] = bias[bn + n0 + 0]; bvals[1] = bias[bn + n0 + 1];
        bvals[2] = bias[bn + n0 + 2]; bvals[3] = bias[bn + n0 + 3];
    }
    #pragma unroll
    for (int i = 0; i < 4; ++i) {
        int r = bm + m0 + i;
        if (r >= M) break;
        float v[4];
        #pragma unroll
        for (int j = 0; j < 4; ++j) {
            float t = acc[i][j] + bvals[j];
            if (ACT == 1) t = (t > 0.f) ? t : (expf(t) - 1.f);
            v[j] = t;
        }
        float4 o = make_float4(v[0], v[1], v[2], v[3]);
        *reinterpret_cast<float4*>(C + (size_t)r * Ncols + bn + n0) = o;
    }
}

// ---------------- per-node attention scalars: el, er ----------------
__global__ __launch_bounds__(256)
void attn_kernel(const float* __restrict__ h, const float* __restrict__ attn_l,
                 const float* __restrict__ attn_r, float* __restrict__ el, float* __restrict__ er)
{
    int node = blockIdx.x * 4 + (threadIdx.x >> 6);
    int lane = threadIdx.x & 63;
    if (node >= NN) return;
    float v = h[(size_t)node * 64 + lane];
    float lr = (v > 0.f) ? v : NSLOPE_C * v;
    float a = lr * attn_l[lane];
    float b = lr * attn_r[lane];
    #pragma unroll
    for (int m = 1; m < 64; m <<= 1) {
        a += __shfl_xor(a, m);
        b += __shfl_xor(b, m);
    }
    if (lane == 0) { el[node] = a; er[node] = b; }
}

// ---------------- edge kernel: ew, deg sums, lp partials ----------------
__global__ __launch_bounds__(256)
void edge_kernel(const int* __restrict__ src, const int* __restrict__ dst,
                 const float* __restrict__ wts,
                 const float* __restrict__ h, const float* __restrict__ hl,
                 const float* __restrict__ el, const float* __restrict__ er,
                 const float* __restrict__ s_attn, const float* __restrict__ beta,
                 const float* __restrict__ aw,
                 float* __restrict__ ew, float* __restrict__ deg_s, float* __restrict__ deg_d,
                 float* __restrict__ lp_part)
{
    int tid = blockIdx.x * 256 + threadIdx.x;
    int e = tid >> 4;            // 16 lanes per edge
    int j = threadIdx.x & 15;
    float lp_p = 0.f, se_p = 0.f, sdf_p = 0.f, sds_p = 0.f;
    int s = 0, d = 0;
    if (e < EE) {
        s = src[e]; d = dst[e];
        const float4 hs = *reinterpret_cast<const float4*>(h  + (size_t)s * 64 + j * 4);
        const float4 hd = *reinterpret_cast<const float4*>(h  + (size_t)d * 64 + j * 4);
        const float4 ls = *reinterpret_cast<const float4*>(hl + (size_t)s * 64 + j * 4);
        const float4 ld = *reinterpret_cast<const float4*>(hl + (size_t)d * 64 + j * 4);
        const float4 sa = *reinterpret_cast<const float4*>(s_attn + j * 4);
        se_p = ls.x * sa.x * ld.x + ls.y * sa.y * ld.y + ls.z * sa.z * ld.z + ls.w * sa.w * ld.w;
        float dx = hs.x - hd.x, dy = hs.y - hd.y, dz = hs.z - hd.z, dw = hs.w - hd.w;
        sdf_p = dx * dx + dy * dy + dz * dz + dw * dw;
        float ex = ls.x - ld.x, ey = ls.y - ld.y, ez = ls.z - ld.z, ec = ls.w - ld.w;
        sds_p = ex * ex + ey * ey + ez * ez + ec * ec;
        float dot = ls.x * ld.x + ls.y * ld.y + ls.z * ld.z + ls.w * ld.w;
        lp_p = dot * wts[e];
    }
    #pragma unroll
    for (int m = 1; m < 16; m <<= 1) {
        se_p  += __shfl_xor(se_p, m);
        sdf_p += __shfl_xor(sdf_p, m);
        sds_p += __shfl_xor(sds_p, m);
    }
    if (e < EE && j == 0) {
        float betaw = 2.f / (expf(-beta[0]) + 1.f);
        float a0 = aw[0], a1 = aw[1];
        float mx = fmaxf(a0, a1);
        float e0 = expf(a0 - mx), e1 = expf(a1 - mx);
        float inv = 1.f / (e0 + e1);
        float w0 = e0 * inv, w1 = e1 * inv;
        float evv = el[s] + er[d] + se_p;
        float dd = w0 * sdf_p + w1 * sds_p;
        float v = expf(evv - betaw * dd) + 1e-9f;
        ew[e] = v;
        atomicAdd(deg_s + s, v);
        atomicAdd(deg_d + d, v);
    }
    // lp: full-wave reduce of per-lane partials (4 edges per wave)
    #pragma unroll
    for (int m = 1; m < 64; m <<= 1) lp_p += __shfl_xor(lp_p, m);
    __shared__ float lred[4];
    if ((threadIdx.x & 63) == 0) lred[threadIdx.x >> 6] = lp_p;
    __syncthreads();
    if (threadIdx.x == 0) lp_part[blockIdx.x] = lred[0] + lred[1] + lred[2] + lred[3];
}

// ---------------- reduce lp partials ----------------
__global__ __launch_bounds__(256)
void reduce_kernel(const float* __restrict__ part, int n, float* __restrict__ out)
{
    float s = 0.f;
    for (int i = threadIdx.x; i < n; i += 256) s += part[i];
    #pragma unroll
    for (int m = 1; m < 64; m <<= 1) s += __shfl_xor(s, m);
    __shared__ float sd[4];
    if ((threadIdx.x & 63) == 0) sd[threadIdx.x >> 6] = s;
    __syncthreads();
    if (threadIdx.x == 0) out[0] = sd[0] + sd[1] + sd[2] + sd[3];
}

// ---------------- edge normalization ----------------
__global__ __launch_bounds__(256)
void wnorm_kernel(const int* __restrict__ src, const int* __restrict__ dst,
                  const float* __restrict__ deg_s, const float* __restrict__ deg_d,
                  const float* __restrict__ theta, float* __restrict__ ew)
{
    int e = blockIdx.x * 256 + threadIdx.x;
    if (e >= EE) return;
    float perm = 1e-9f / (expf(-theta[0]) + 1.f);
    float v = ew[e] * rsqrtf(deg_s[src[e]]) * rsqrtf(deg_d[dst[e]]) + perm;
    ew[e] = v;
}

// ---------------- CSR build ----------------
__global__ __launch_bounds__(256)
void count_kernel(const int* __restrict__ dst, int* __restrict__ cnt)
{
    int e = blockIdx.x * 256 + threadIdx.x;
    if (e < EE) atomicAdd(cnt + dst[e], 1);
}

__global__ __launch_bounds__(1024)
void scan_kernel(const int* __restrict__ cnt, int* __restrict__ row, int* __restrict__ cur)
{
    __shared__ int sums[1024];
    int t = threadIdx.x;
    const int CH = (NN + 1023) / 1024;
    int lo = t * CH, hi = min(lo + CH, NN);
    int s = 0;
    for (int i = lo; i < hi; ++i) s += cnt[i];
    sums[t] = s;
    __syncthreads();
    for (int off = 1; off < 1024; off <<= 1) {
        int add = (t >= off) ? sums[t - off] : 0;
        __syncthreads();
        sums[t] += add;
        __syncthreads();
    }
    int running = sums[t] - s;  // exclusive base
    for (int i = lo; i < hi; ++i) {
        row[i] = running;
        cur[i] = running;
        running += cnt[i];
    }
    if (t == 1023) row[NN] = sums[1023];
}

__global__ __launch_bounds__(256)
void bucket_kernel(const int* __restrict__ src, const int* __restrict__ dst,
                   const float* __restrict__ w, int* __restrict__ cur,
                   int* __restrict__ csr_src, float* __restrict__ csr_w)
{
    int e = blockIdx.x * 256 + threadIdx.x;
    if (e >= EE) return;
    int d = dst[e];
    int pos = atomicAdd(cur + d, 1);
    csr_src[pos] = src[e];
    csr_w[pos] = (1.0f - ALPHA_C) * w[e];
}

// ---------------- propagation: fout = 0.9*sum(w*fin[src]) + 0.1*h (0.9 folded into csr_w) ----
// One wave per node. Lane layout: sub = lane>>4 (4 edges in flight), f = lane&15
// (float4 feature group). Each loop iteration gathers 4 full 256 B rows via
// 16-lane float4 loads -> 4 independent memory streams, 16 B/lane coalescing.
__global__ __launch_bounds__(256)
void prop_kernel(const float* __restrict__ fin, const float* __restrict__ h,
                 const int* __restrict__ row, const int* __restrict__ csr_src,
                 const float* __restrict__ csr_w, float* __restrict__ fout)
{
    int node = blockIdx.x * 4 + (threadIdx.x >> 6);
    int lane = threadIdx.x & 63;
    int sub = lane >> 4;
    int f = lane & 15;
    if (node >= NN) return;
    int b = row[node], en = row[node + 1];
    float4 acc = make_float4(0.f, 0.f, 0.f, 0.f);
    for (int e = b + sub; e < en; e += 4) {
        int s = csr_src[e];          // broadcast across the 16 f-lanes of this sub
        float wv = csr_w[e];
        const float4 v = *reinterpret_cast<const float4*>(fin + (size_t)s * 64 + f * 4);
        acc.x = fmaf(wv, v.x, acc.x);
        acc.y = fmaf(wv, v.y, acc.y);
        acc.z = fmaf(wv, v.z, acc.z);
        acc.w = fmaf(wv, v.w, acc.w);
    }
    // reduce the 4 sub-partials (xor 16, 32)
    #pragma unroll
    for (int m = 16; m < 64; m <<= 1) {
        acc.x += __shfl_xor(acc.x, m);
        acc.y += __shfl_xor(acc.y, m);
        acc.z += __shfl_xor(acc.z, m);
        acc.w += __shfl_xor(acc.w, m);
    }
    if (sub == 0) {
        const float4 hv = *reinterpret_cast<const float4*>(h + (size_t)node * 64 + f * 4);
        float4 o;
        o.x = fmaf(ALPHA_C, hv.x, acc.x);
        o.y = fmaf(ALPHA_C, hv.y, acc.y);
        o.z = fmaf(ALPHA_C, hv.z, acc.z);
        o.w = fmaf(ALPHA_C, hv.w, acc.w);
        *reinterpret_cast<float4*>(fout + (size_t)node * 64 + f * 4) = o;
    }
}

// ---------------- epilogue: out = log_softmax(elu(fp)) ----------------
__global__ __launch_bounds__(256)
void out_kernel(const float* __restrict__ fp, float* __restrict__ out)
{
    int node = blockIdx.x * 4 + (threadIdx.x >> 6);
    int lane = threadIdx.x & 63;
    if (node >= NN) return;
    float v = fp[(size_t)node * 64 + lane];
    float ev = (v > 0.f) ? v : (expf(v) - 1.f);
    float m = ev;
    #pragma unroll
    for (int k = 1; k < 64; k <<= 1) m = fmaxf(m, __shfl_xor(m, k));
    float s = expf(ev - m);
    #pragma unroll
    for (int k = 1; k < 64; k <<= 1) s += __shfl_xor(s, k);
    out[(size_t)node * 64 + lane] = ev - m - logf(s);
}

extern "C" void kernel_launch(void* const* d_in, const int* in_sizes, int n_in,
                              void* d_out, int out_size, void* d_ws, size_t ws_size,
                              hipStream_t stream)
{
    const float* x      = (const float*)d_in[0];
    const int*   src    = (const int*)d_in[1];
    const int*   dst    = (const int*)d_in[2];
    const float* wts    = (const float*)d_in[3];
    const float* latp   = (const float*)d_in[4];
    const float* W_in   = (const float*)d_in[5];
    const float* W_out  = (const float*)d_in[6];
    const float* Ws1    = (const float*)d_in[7];
    const float* b1     = (const float*)d_in[8];
    const float* Ws2    = (const float*)d_in[9];
    const float* b2     = (const float*)d_in[10];
    const float* attn_l = (const float*)d_in[11];
    const float* attn_r = (const float*)d_in[12];
    const float* s_attn = (const float*)d_in[13];
    const float* beta   = (const float*)d_in[14];
    const float* theta  = (const float*)d_in[15];
    const float* aw     = (const float*)d_in[16];

    float* out = (float*)d_out;
    float* lp  = out + (size_t)NN * 64;

    char* w8 = (char*)d_ws;
    size_t off = 0;
    auto alloc = [&](size_t bytes) -> char* {
        char* p = w8 + off;
        off += (bytes + 255) / 256 * 256;
        return p;
    };
    float* big    = (float*)alloc((size_t)NN * 256 * 4);
    float* h1     = big;
    float* hl_tmp = big;
    float* fpA    = big;
    float* fpB    = big + (size_t)NN * 64;
    float* h      = (float*)alloc((size_t)NN * 64 * 4);
    float* hl     = (float*)alloc((size_t)NN * 64 * 4);
    float* ew     = (float*)alloc((size_t)EE * 4);
    float* el     = (float*)alloc((size_t)NN * 4);
    float* er     = (float*)alloc((size_t)NN * 4);
    float* deg_s  = (float*)alloc((size_t)NN * 4);
    float* deg_d  = (float*)alloc((size_t)NN * 4);
    int*   cnt    = (int*)alloc((size_t)NN * 4);
    int*   row    = (int*)alloc((size_t)(NN + 1) * 4);
    int*   cur    = (int*)alloc((size_t)NN * 4);
    int*   csr_src= (int*)alloc((size_t)EE * 4);
    float* csr_w  = (float*)alloc((size_t)EE * 4);
    float* lp_part= (float*)alloc((size_t)100000 * 4);

    hipMemsetAsync(cnt,   0, (size_t)NN * 4, stream);
    hipMemsetAsync(deg_s, 0, (size_t)NN * 4, stream);
    hipMemsetAsync(deg_d, 0, (size_t)NN * 4, stream);

    const int MB = (NN + 63) / 64;  // 1563
    gemm_kernel<1><<<dim3(MB, NHIDC / 64), 256, 0, stream>>>(x, W_in, nullptr, h1, NN, NFEATC, NHIDC);
    gemm_kernel<0><<<dim3(MB, 1), 256, 0, stream>>>(h1, W_out, nullptr, h, NN, NHIDC, NCC);
    gemm_kernel<1><<<dim3(MB, 1), 256, 0, stream>>>(latp, Ws1, b1, hl_tmp, NN, NCC, NCC);
    gemm_kernel<1><<<dim3(MB, 1), 256, 0, stream>>>(hl_tmp, Ws2, b2, hl, NN, NCC, NCC);

    attn_kernel<<<NN / 4, 256, 0, stream>>>(h, attn_l, attn_r, el, er);
    count_kernel<<<EE / 256, 256, 0, stream>>>(dst, cnt);
    scan_kernel<<<1, 1024, 0, stream>>>(cnt, row, cur);

    edge_kernel<<<EE * 16 / 256, 256, 0, stream>>>(src, dst, wts, h, hl, el, er,
                                                   s_attn, beta, aw, ew, deg_s, deg_d, lp_part);
    reduce_kernel<<<1, 256, 0, stream>>>(lp_part, EE * 16 / 256 > 100000 ? 100000 : EE * 16 / 256, lp);

    wnorm_kernel<<<EE / 256, 256, 0, stream>>>(src, dst, deg_s, deg_d, theta, ew);
    bucket_kernel<<<EE / 256, 256, 0, stream>>>(src, dst, ew, cur, csr_src, csr_w);

    const float* fin = h;
    float* bufs[2] = {fpA, fpB};
    for (int it = 0; it < 8; ++it) {
        float* fo = bufs[it & 1];
        prop_kernel<<<NN / 4, 256, 0, stream>>>(fin, h, row, csr_src, csr_w, fo);
        fin = fo;
    }
    out_kernel<<<NN / 4, 256, 0, stream>>>(fin, out);
}

// Round 3
// 1815.796 us; speedup vs baseline: 1.4842x; 1.1134x over previous
//
#include <hip/hip_runtime.h>
#include <math.h>

#define NN 100000
#define EE 1600000
#define NFEATC 512
#define NHIDC 256
#define NCC 64
#define ALPHA_C 0.1f
#define NSLOPE_C 0.2f

typedef __attribute__((ext_vector_type(8))) short short8;
typedef __attribute__((ext_vector_type(4))) float floatx4;

__device__ __forceinline__ short f2bf(float f) {
    unsigned u = __float_as_uint(f);
    unsigned r = (u + 0x7FFFu + ((u >> 16) & 1u)) >> 16;   // RNE
    return (short)r;
}

// ---------------- W_in transpose-cast: W[512][256] fp32 -> WT[256][512] bf16 ----------------
__global__ __launch_bounds__(256)
void castWT_kernel(const float* __restrict__ W, short* __restrict__ WT, int K, int Ncols)
{
    int k = blockIdx.x;
    int n = threadIdx.x;
    if (k < K && n < Ncols)
        WT[(size_t)n * K + k] = f2bf(W[(size_t)k * Ncols + n]);
}

// ---------------- gemm1: h1 = elu(x @ W_in)  via bf16 MFMA ----------------
// M=100000 K=512 N=256. Tile BM=128 x BN=256 (one column block -> A read once).
// BK=32. 256 threads = 4 waves as 2x2; each wave computes 64 rows x 128 cols
// = 4x8 grid of 16x16x32 MFMAs. A staged fp32->bf16 in-register; B pre-cast
// to WT bf16 [N][K]. LDS padded +8 shorts (legal: VGPR staging, not
// global_load_lds) -> ds_read row stride 80 B, 2-way banks (free).
__global__ __launch_bounds__(256)
void gemm1_mfma_kernel(const float* __restrict__ x, const short* __restrict__ WT,
                       float* __restrict__ h1, int M)
{
    __shared__ short As[128][40];
    __shared__ short Bs[256][40];
    const int tid = threadIdx.x;
    const int bm = blockIdx.x * 128;
    const int wave = tid >> 6;
    const int lane = tid & 63;
    const int wm = wave >> 1;          // 0/1: row half
    const int wn = wave & 1;           // 0/1: col half
    const int l16 = lane & 15;
    const int quad = lane >> 4;

    floatx4 acc[4][8];
    #pragma unroll
    for (int i = 0; i < 4; ++i)
        #pragma unroll
        for (int j = 0; j < 8; ++j)
            acc[i][j] = (floatx4){0.f, 0.f, 0.f, 0.f};

    // staging roles
    const int ar = tid >> 1;           // A row 0..127
    const int ah = tid & 1;            // A k-half (16 floats)
    const int xrow = bm + ar;
    const float* xp = x + (size_t)xrow * NFEATC + ah * 16;
    const short* wp = WT + (size_t)tid * NFEATC;   // B row n = tid

    for (int kt = 0; kt < NFEATC; kt += 32) {
        // global loads (A fp32, B bf16)
        float4 a0, a1, a2, a3;
        if (xrow < M) {
            a0 = *reinterpret_cast<const float4*>(xp + kt + 0);
            a1 = *reinterpret_cast<const float4*>(xp + kt + 4);
            a2 = *reinterpret_cast<const float4*>(xp + kt + 8);
            a3 = *reinterpret_cast<const float4*>(xp + kt + 12);
        } else {
            a0 = a1 = a2 = a3 = make_float4(0.f, 0.f, 0.f, 0.f);
        }
        const short8* wq = reinterpret_cast<const short8*>(wp + kt);
        short8 b0 = wq[0], b1 = wq[1], b2 = wq[2], b3 = wq[3];

        short8 s0, s1;
        s0[0] = f2bf(a0.x); s0[1] = f2bf(a0.y); s0[2] = f2bf(a0.z); s0[3] = f2bf(a0.w);
        s0[4] = f2bf(a1.x); s0[5] = f2bf(a1.y); s0[6] = f2bf(a1.z); s0[7] = f2bf(a1.w);
        s1[0] = f2bf(a2.x); s1[1] = f2bf(a2.y); s1[2] = f2bf(a2.z); s1[3] = f2bf(a2.w);
        s1[4] = f2bf(a3.x); s1[5] = f2bf(a3.y); s1[6] = f2bf(a3.z); s1[7] = f2bf(a3.w);

        __syncthreads();   // protect previous iteration's LDS reads
        *reinterpret_cast<short8*>(&As[ar][ah * 16 + 0]) = s0;
        *reinterpret_cast<short8*>(&As[ar][ah * 16 + 8]) = s1;
        *reinterpret_cast<short8*>(&Bs[tid][0])  = b0;
        *reinterpret_cast<short8*>(&Bs[tid][8])  = b1;
        *reinterpret_cast<short8*>(&Bs[tid][16]) = b2;
        *reinterpret_cast<short8*>(&Bs[tid][24]) = b3;
        __syncthreads();

        short8 af[4], bf[8];
        #pragma unroll
        for (int mi = 0; mi < 4; ++mi)
            af[mi] = *reinterpret_cast<const short8*>(&As[wm * 64 + mi * 16 + l16][quad * 8]);
        #pragma unroll
        for (int ni = 0; ni < 8; ++ni)
            bf[ni] = *reinterpret_cast<const short8*>(&Bs[wn * 128 + ni * 16 + l16][quad * 8]);
        #pragma unroll
        for (int mi = 0; mi < 4; ++mi)
            #pragma unroll
            for (int ni = 0; ni < 8; ++ni)
                acc[mi][ni] = __builtin_amdgcn_mfma_f32_16x16x32_bf16(af[mi], bf[ni], acc[mi][ni], 0, 0, 0);
    }

    // epilogue: elu, store fp32. C layout: row = quad*4+r, col = l16
    #pragma unroll
    for (int mi = 0; mi < 4; ++mi) {
        #pragma unroll
        for (int r = 0; r < 4; ++r) {
            int row = bm + wm * 64 + mi * 16 + quad * 4 + r;
            if (row >= M) continue;
            float* outp = h1 + (size_t)row * NHIDC + wn * 128 + l16;
            #pragma unroll
            for (int ni = 0; ni < 8; ++ni) {
                float v = acc[mi][ni][r];
                v = (v > 0.f) ? v : (expf(v) - 1.f);
                outp[ni * 16] = v;
            }
        }
    }
}

// ---------------- GEMM: C = act(A@B + bias), tile 64x64, KT=16, 256 thr, 4x4 micro ----------------
template<int ACT>  // 0 = none, 1 = elu
__global__ __launch_bounds__(256)
void gemm_kernel(const float* __restrict__ A, const float* __restrict__ B,
                 const float* __restrict__ bias, float* __restrict__ C,
                 int M, int K, int Ncols)
{
    __shared__ float As[16][68];
    __shared__ float Bs[16][64];
    const int tid = threadIdx.x;
    const int bm = blockIdx.x * 64;
    const int bn = blockIdx.y * 64;
    const int m0 = (tid & 15) * 4;
    const int n0 = (tid >> 4) * 4;
    float acc[4][4] = {};

    const int am = bm + (tid >> 2);
    const int ak = (tid & 3) * 4;
    const int bk = tid >> 4;
    const int bn4 = bn + (tid & 15) * 4;

    for (int kt = 0; kt < K; kt += 16) {
        float4 av;
        if (am < M) av = *reinterpret_cast<const float4*>(A + (size_t)am * K + kt + ak);
        else        av = make_float4(0.f, 0.f, 0.f, 0.f);
        float4 bv = *reinterpret_cast<const float4*>(B + (size_t)(kt + bk) * Ncols + bn4);
        __syncthreads();
        As[ak + 0][tid >> 2] = av.x;
        As[ak + 1][tid >> 2] = av.y;
        As[ak + 2][tid >> 2] = av.z;
        As[ak + 3][tid >> 2] = av.w;
        *reinterpret_cast<float4*>(&Bs[bk][(tid & 15) * 4]) = bv;
        __syncthreads();
        #pragma unroll
        for (int k = 0; k < 16; ++k) {
            float4 a4 = *reinterpret_cast<const float4*>(&As[k][m0]);
            float4 b4 = *reinterpret_cast<const float4*>(&Bs[k][n0]);
            float a_[4] = {a4.x, a4.y, a4.z, a4.w};
            float b_[4] = {b4.x, b4.y, b4.z, b4.w};
            #pragma unroll
            for (int i = 0; i < 4; ++i)
                #pragma unroll
                for (int j = 0; j < 4; ++j)
                    acc[i][j] = fmaf(a_[i], b_[j], acc[i][j]);
        }
    }

    float bvals[4] = {0.f, 0.f, 0.f, 0.f};
    if (bias) {
        bvals[0] = bias[bn + n0 + 0]; bvals[1] = bias[bn + n0 + 1];
        bvals[2] = bias[bn + n0 + 2]; bvals[3] = bias[bn + n0 + 3];
    }
    #pragma unroll
    for (int i = 0; i < 4; ++i) {
        int r = bm + m0 + i;
        if (r >= M) break;
        float v[4];
        #pragma unroll
        for (int j = 0; j < 4; ++j) {
            float t = acc[i][j] + bvals[j];
            if (ACT == 1) t = (t > 0.f) ? t : (expf(t) - 1.f);
            v[j] = t;
        }
        float4 o = make_float4(v[0], v[1], v[2], v[3]);
        *reinterpret_cast<float4*>(C + (size_t)r * Ncols + bn + n0) = o;
    }
}

// ---------------- per-node attention scalars: el, er ----------------
__global__ __launch_bounds__(256)
void attn_kernel(const float* __restrict__ h, const float* __restrict__ attn_l,
                 const float* __restrict__ attn_r, float* __restrict__ el, float* __restrict__ er)
{
    int node = blockIdx.x * 4 + (threadIdx.x >> 6);
    int lane = threadIdx.x & 63;
    if (node >= NN) return;
    float v = h[(size_t)node * 64 + lane];
    float lr = (v > 0.f) ? v : NSLOPE_C * v;
    float a = lr * attn_l[lane];
    float b = lr * attn_r[lane];
    #pragma unroll
    for (int m = 1; m < 64; m <<= 1) {
        a += __shfl_xor(a, m);
        b += __shfl_xor(b, m);
    }
    if (lane == 0) { el[node] = a; er[node] = b; }
}

// ---------------- edge kernel: ew, deg sums, lp partials ----------------
__global__ __launch_bounds__(256)
void edge_kernel(const int* __restrict__ src, const int* __restrict__ dst,
                 const float* __restrict__ wts,
                 const float* __restrict__ h, const float* __restrict__ hl,
                 const float* __restrict__ el, const float* __restrict__ er,
                 const float* __restrict__ s_attn, const float* __restrict__ beta,
                 const float* __restrict__ aw,
                 float* __restrict__ ew, float* __restrict__ deg_s, float* __restrict__ deg_d,
                 float* __restrict__ lp_part)
{
    int tid = blockIdx.x * 256 + threadIdx.x;
    int e = tid >> 4;
    int j = threadIdx.x & 15;
    float lp_p = 0.f, se_p = 0.f, sdf_p = 0.f, sds_p = 0.f;
    int s = 0, d = 0;
    if (e < EE) {
        s = src[e]; d = dst[e];
        const float4 hs = *reinterpret_cast<const float4*>(h  + (size_t)s * 64 + j * 4);
        const float4 hd = *reinterpret_cast<const float4*>(h  + (size_t)d * 64 + j * 4);
        const float4 ls = *reinterpret_cast<const float4*>(hl + (size_t)s * 64 + j * 4);
        const float4 ld = *reinterpret_cast<const float4*>(hl + (size_t)d * 64 + j * 4);
        const float4 sa = *reinterpret_cast<const float4*>(s_attn + j * 4);
        se_p = ls.x * sa.x * ld.x + ls.y * sa.y * ld.y + ls.z * sa.z * ld.z + ls.w * sa.w * ld.w;
        float dx = hs.x - hd.x, dy = hs.y - hd.y, dz = hs.z - hd.z, dw = hs.w - hd.w;
        sdf_p = dx * dx + dy * dy + dz * dz + dw * dw;
        float ex = ls.x - ld.x, ey = ls.y - ld.y, ez = ls.z - ld.z, ec = ls.w - ld.w;
        sds_p = ex * ex + ey * ey + ez * ez + ec * ec;
        float dot = ls.x * ld.x + ls.y * ld.y + ls.z * ld.z + ls.w * ld.w;
        lp_p = dot * wts[e];
    }
    #pragma unroll
    for (int m = 1; m < 16; m <<= 1) {
        se_p  += __shfl_xor(se_p, m);
        sdf_p += __shfl_xor(sdf_p, m);
        sds_p += __shfl_xor(sds_p, m);
    }
    if (e < EE && j == 0) {
        float betaw = 2.f / (expf(-beta[0]) + 1.f);
        float a0 = aw[0], a1 = aw[1];
        float mx = fmaxf(a0, a1);
        float e0 = expf(a0 - mx), e1 = expf(a1 - mx);
        float inv = 1.f / (e0 + e1);
        float w0 = e0 * inv, w1 = e1 * inv;
        float evv = el[s] + er[d] + se_p;
        float dd = w0 * sdf_p + w1 * sds_p;
        float v = expf(evv - betaw * dd) + 1e-9f;
        ew[e] = v;
        atomicAdd(deg_s + s, v);
        atomicAdd(deg_d + d, v);
    }
    #pragma unroll
    for (int m = 1; m < 64; m <<= 1) lp_p += __shfl_xor(lp_p, m);
    __shared__ float lred[4];
    if ((threadIdx.x & 63) == 0) lred[threadIdx.x >> 6] = lp_p;
    __syncthreads();
    if (threadIdx.x == 0) lp_part[blockIdx.x] = lred[0] + lred[1] + lred[2] + lred[3];
}

// ---------------- reduce lp partials ----------------
__global__ __launch_bounds__(256)
void reduce_kernel(const float* __restrict__ part, int n, float* __restrict__ out)
{
    float s = 0.f;
    for (int i = threadIdx.x; i < n; i += 256) s += part[i];
    #pragma unroll
    for (int m = 1; m < 64; m <<= 1) s += __shfl_xor(s, m);
    __shared__ float sd[4];
    if ((threadIdx.x & 63) == 0) sd[threadIdx.x >> 6] = s;
    __syncthreads();
    if (threadIdx.x == 0) out[0] = sd[0] + sd[1] + sd[2] + sd[3];
}

// ---------------- edge normalization ----------------
__global__ __launch_bounds__(256)
void wnorm_kernel(const int* __restrict__ src, const int* __restrict__ dst,
                  const float* __restrict__ deg_s, const float* __restrict__ deg_d,
                  const float* __restrict__ theta, float* __restrict__ ew)
{
    int e = blockIdx.x * 256 + threadIdx.x;
    if (e >= EE) return;
    float perm = 1e-9f / (expf(-theta[0]) + 1.f);
    float v = ew[e] * rsqrtf(deg_s[src[e]]) * rsqrtf(deg_d[dst[e]]) + perm;
    ew[e] = v;
}

// ---------------- CSR build ----------------
__global__ __launch_bounds__(256)
void count_kernel(const int* __restrict__ dst, int* __restrict__ cnt)
{
    int e = blockIdx.x * 256 + threadIdx.x;
    if (e < EE) atomicAdd(cnt + dst[e], 1);
}

__global__ __launch_bounds__(1024)
void scan_kernel(const int* __restrict__ cnt, int* __restrict__ row, int* __restrict__ cur)
{
    __shared__ int sums[1024];
    int t = threadIdx.x;
    const int CH = (NN + 1023) / 1024;
    int lo = t * CH, hi = min(lo + CH, NN);
    int s = 0;
    for (int i = lo; i < hi; ++i) s += cnt[i];
    sums[t] = s;
    __syncthreads();
    for (int off = 1; off < 1024; off <<= 1) {
        int add = (t >= off) ? sums[t - off] : 0;
        __syncthreads();
        sums[t] += add;
        __syncthreads();
    }
    int running = sums[t] - s;
    for (int i = lo; i < hi; ++i) {
        row[i] = running;
        cur[i] = running;
        running += cnt[i];
    }
    if (t == 1023) row[NN] = sums[1023];
}

__global__ __launch_bounds__(256)
void bucket_kernel(const int* __restrict__ src, const int* __restrict__ dst,
                   const float* __restrict__ w, int* __restrict__ cur,
                   int* __restrict__ csr_src, float* __restrict__ csr_w)
{
    int e = blockIdx.x * 256 + threadIdx.x;
    if (e >= EE) return;
    int d = dst[e];
    int pos = atomicAdd(cur + d, 1);
    csr_src[pos] = src[e];
    csr_w[pos] = (1.0f - ALPHA_C) * w[e];
}

// ---------------- propagation ----------------
__global__ __launch_bounds__(256)
void prop_kernel(const float* __restrict__ fin, const float* __restrict__ h,
                 const int* __restrict__ row, const int* __restrict__ csr_src,
                 const float* __restrict__ csr_w, float* __restrict__ fout)
{
    int node = blockIdx.x * 4 + (threadIdx.x >> 6);
    int lane = threadIdx.x & 63;
    int sub = lane >> 4;
    int f = lane & 15;
    if (node >= NN) return;
    int b = row[node], en = row[node + 1];
    float4 acc = make_float4(0.f, 0.f, 0.f, 0.f);
    for (int e = b + sub; e < en; e += 4) {
        int s = csr_src[e];
        float wv = csr_w[e];
        const float4 v = *reinterpret_cast<const float4*>(fin + (size_t)s * 64 + f * 4);
        acc.x = fmaf(wv, v.x, acc.x);
        acc.y = fmaf(wv, v.y, acc.y);
        acc.z = fmaf(wv, v.z, acc.z);
        acc.w = fmaf(wv, v.w, acc.w);
    }
    #pragma unroll
    for (int m = 16; m < 64; m <<= 1) {
        acc.x += __shfl_xor(acc.x, m);
        acc.y += __shfl_xor(acc.y, m);
        acc.z += __shfl_xor(acc.z, m);
        acc.w += __shfl_xor(acc.w, m);
    }
    if (sub == 0) {
        const float4 hv = *reinterpret_cast<const float4*>(h + (size_t)node * 64 + f * 4);
        float4 o;
        o.x = fmaf(ALPHA_C, hv.x, acc.x);
        o.y = fmaf(ALPHA_C, hv.y, acc.y);
        o.z = fmaf(ALPHA_C, hv.z, acc.z);
        o.w = fmaf(ALPHA_C, hv.w, acc.w);
        *reinterpret_cast<float4*>(fout + (size_t)node * 64 + f * 4) = o;
    }
}

// ---------------- epilogue: out = log_softmax(elu(fp)) ----------------
__global__ __launch_bounds__(256)
void out_kernel(const float* __restrict__ fp, float* __restrict__ out)
{
    int node = blockIdx.x * 4 + (threadIdx.x >> 6);
    int lane = threadIdx.x & 63;
    if (node >= NN) return;
    float v = fp[(size_t)node * 64 + lane];
    float ev = (v > 0.f) ? v : (expf(v) - 1.f);
    float m = ev;
    #pragma unroll
    for (int k = 1; k < 64; k <<= 1) m = fmaxf(m, __shfl_xor(m, k));
    float s = expf(ev - m);
    #pragma unroll
    for (int k = 1; k < 64; k <<= 1) s += __shfl_xor(s, k);
    out[(size_t)node * 64 + lane] = ev - m - logf(s);
}

extern "C" void kernel_launch(void* const* d_in, const int* in_sizes, int n_in,
                              void* d_out, int out_size, void* d_ws, size_t ws_size,
                              hipStream_t stream)
{
    const float* x      = (const float*)d_in[0];
    const int*   src    = (const int*)d_in[1];
    const int*   dst    = (const int*)d_in[2];
    const float* wts    = (const float*)d_in[3];
    const float* latp   = (const float*)d_in[4];
    const float* W_in   = (const float*)d_in[5];
    const float* W_out  = (const float*)d_in[6];
    const float* Ws1    = (const float*)d_in[7];
    const float* b1     = (const float*)d_in[8];
    const float* Ws2    = (const float*)d_in[9];
    const float* b2     = (const float*)d_in[10];
    const float* attn_l = (const float*)d_in[11];
    const float* attn_r = (const float*)d_in[12];
    const float* s_attn = (const float*)d_in[13];
    const float* beta   = (const float*)d_in[14];
    const float* theta  = (const float*)d_in[15];
    const float* aw     = (const float*)d_in[16];

    float* out = (float*)d_out;
    float* lp  = out + (size_t)NN * 64;

    char* w8 = (char*)d_ws;
    size_t off = 0;
    auto alloc = [&](size_t bytes) -> char* {
        char* p = w8 + off;
        off += (bytes + 255) / 256 * 256;
        return p;
    };
    float* big    = (float*)alloc((size_t)NN * 256 * 4);
    float* h1     = big;
    float* hl_tmp = big;
    float* fpA    = big;
    float* fpB    = big + (size_t)NN * 64;
    float* h      = (float*)alloc((size_t)NN * 64 * 4);
    float* hl     = (float*)alloc((size_t)NN * 64 * 4);
    float* ew     = (float*)alloc((size_t)EE * 4);
    float* el     = (float*)alloc((size_t)NN * 4);
    float* er     = (float*)alloc((size_t)NN * 4);
    float* deg_s  = (float*)alloc((size_t)NN * 4);
    float* deg_d  = (float*)alloc((size_t)NN * 4);
    int*   cnt    = (int*)alloc((size_t)NN * 4);
    int*   row    = (int*)alloc((size_t)(NN + 1) * 4);
    int*   cur    = (int*)alloc((size_t)NN * 4);
    int*   csr_src= (int*)alloc((size_t)EE * 4);
    float* csr_w  = (float*)alloc((size_t)EE * 4);
    float* lp_part= (float*)alloc((size_t)100000 * 4);
    short* WT     = (short*)alloc((size_t)NHIDC * NFEATC * 2);   // W_in^T bf16 [256][512]

    hipMemsetAsync(cnt,   0, (size_t)NN * 4, stream);
    hipMemsetAsync(deg_s, 0, (size_t)NN * 4, stream);
    hipMemsetAsync(deg_d, 0, (size_t)NN * 4, stream);

    const int MB = (NN + 63) / 64;  // 1563

    // h1 = elu(x @ W_in)  -- bf16 MFMA path
    castWT_kernel<<<NFEATC, 256, 0, stream>>>(W_in, WT, NFEATC, NHIDC);
    gemm1_mfma_kernel<<<(NN + 127) / 128, 256, 0, stream>>>(x, WT, h1, NN);

    gemm_kernel<0><<<dim3(MB, 1), 256, 0, stream>>>(h1, W_out, nullptr, h, NN, NHIDC, NCC);
    gemm_kernel<1><<<dim3(MB, 1), 256, 0, stream>>>(latp, Ws1, b1, hl_tmp, NN, NCC, NCC);
    gemm_kernel<1><<<dim3(MB, 1), 256, 0, stream>>>(hl_tmp, Ws2, b2, hl, NN, NCC, NCC);

    attn_kernel<<<NN / 4, 256, 0, stream>>>(h, attn_l, attn_r, el, er);
    count_kernel<<<EE / 256, 256, 0, stream>>>(dst, cnt);
    scan_kernel<<<1, 1024, 0, stream>>>(cnt, row, cur);

    edge_kernel<<<EE * 16 / 256, 256, 0, stream>>>(src, dst, wts, h, hl, el, er,
                                                   s_attn, beta, aw, ew, deg_s, deg_d, lp_part);
    reduce_kernel<<<1, 256, 0, stream>>>(lp_part, EE * 16 / 256 > 100000 ? 100000 : EE * 16 / 256, lp);

    wnorm_kernel<<<EE / 256, 256, 0, stream>>>(src, dst, deg_s, deg_d, theta, ew);
    bucket_kernel<<<EE / 256, 256, 0, stream>>>(src, dst, ew, cur, csr_src, csr_w);

    const float* fin = h;
    float* bufs[2] = {fpA, fpB};
    for (int it = 0; it < 8; ++it) {
        float* fo = bufs[it & 1];
        prop_kernel<<<NN / 4, 256, 0, stream>>>(fin, h, row, csr_src, csr_w, fo);
        fin = fo;
    }
    out_kernel<<<NN / 4, 256, 0, stream>>>(fin, out);
}

// Round 4
// 1766.863 us; speedup vs baseline: 1.5253x; 1.0277x over previous
//
#include <hip/hip_runtime.h>
#include <math.h>

#define NN 100000
#define EE 1600000
#define NFEATC 512
#define NHIDC 256
#define NCC 64
#define ALPHA_C 0.1f
#define NSLOPE_C 0.2f

typedef __attribute__((ext_vector_type(8))) short short8;
typedef __attribute__((ext_vector_type(4))) short short4v;
typedef __attribute__((ext_vector_type(4))) float floatx4;

__device__ __forceinline__ short f2bf(float f) {
    unsigned u = __float_as_uint(f);
    unsigned r = (u + 0x7FFFu + ((u >> 16) & 1u)) >> 16;   // RNE
    return (short)r;
}
__device__ __forceinline__ float bf2f(short s) {
    return __uint_as_float(((unsigned)(unsigned short)s) << 16);
}

// ---------------- W_in transpose-cast: W[512][256] fp32 -> WT[256][512] bf16 ----------------
__global__ __launch_bounds__(256)
void castWT_kernel(const float* __restrict__ W, short* __restrict__ WT, int K, int Ncols)
{
    int k = blockIdx.x;
    int n = threadIdx.x;
    if (k < K && n < Ncols)
        WT[(size_t)n * K + k] = f2bf(W[(size_t)k * Ncols + n]);
}

// ---------------- elementwise fp32 -> bf16 cast (vectorized 4/thread) ----------------
__global__ __launch_bounds__(256)
void cast_bf_kernel(const float* __restrict__ in, short* __restrict__ out, int n4)
{
    int i = blockIdx.x * 256 + threadIdx.x;
    if (i >= n4) return;
    float4 v = reinterpret_cast<const float4*>(in)[i];
    short4v o;
    o[0] = f2bf(v.x); o[1] = f2bf(v.y); o[2] = f2bf(v.z); o[3] = f2bf(v.w);
    reinterpret_cast<short4v*>(out)[i] = o;
}

// ---------------- gemm1: h1 = elu(x @ W_in)  via bf16 MFMA ----------------
__global__ __launch_bounds__(256)
void gemm1_mfma_kernel(const float* __restrict__ x, const short* __restrict__ WT,
                       float* __restrict__ h1, int M)
{
    __shared__ short As[128][40];
    __shared__ short Bs[256][40];
    const int tid = threadIdx.x;
    const int bm = blockIdx.x * 128;
    const int wave = tid >> 6;
    const int lane = tid & 63;
    const int wm = wave >> 1;
    const int wn = wave & 1;
    const int l16 = lane & 15;
    const int quad = lane >> 4;

    floatx4 acc[4][8];
    #pragma unroll
    for (int i = 0; i < 4; ++i)
        #pragma unroll
        for (int j = 0; j < 8; ++j)
            acc[i][j] = (floatx4){0.f, 0.f, 0.f, 0.f};

    const int ar = tid >> 1;
    const int ah = tid & 1;
    const int xrow = bm + ar;
    const float* xp = x + (size_t)xrow * NFEATC + ah * 16;
    const short* wp = WT + (size_t)tid * NFEATC;

    for (int kt = 0; kt < NFEATC; kt += 32) {
        float4 a0, a1, a2, a3;
        if (xrow < M) {
            a0 = *reinterpret_cast<const float4*>(xp + kt + 0);
            a1 = *reinterpret_cast<const float4*>(xp + kt + 4);
            a2 = *reinterpret_cast<const float4*>(xp + kt + 8);
            a3 = *reinterpret_cast<const float4*>(xp + kt + 12);
        } else {
            a0 = a1 = a2 = a3 = make_float4(0.f, 0.f, 0.f, 0.f);
        }
        const short8* wq = reinterpret_cast<const short8*>(wp + kt);
        short8 b0 = wq[0], b1 = wq[1], b2 = wq[2], b3 = wq[3];

        short8 s0, s1;
        s0[0] = f2bf(a0.x); s0[1] = f2bf(a0.y); s0[2] = f2bf(a0.z); s0[3] = f2bf(a0.w);
        s0[4] = f2bf(a1.x); s0[5] = f2bf(a1.y); s0[6] = f2bf(a1.z); s0[7] = f2bf(a1.w);
        s1[0] = f2bf(a2.x); s1[1] = f2bf(a2.y); s1[2] = f2bf(a2.z); s1[3] = f2bf(a2.w);
        s1[4] = f2bf(a3.x); s1[5] = f2bf(a3.y); s1[6] = f2bf(a3.z); s1[7] = f2bf(a3.w);

        __syncthreads();
        *reinterpret_cast<short8*>(&As[ar][ah * 16 + 0]) = s0;
        *reinterpret_cast<short8*>(&As[ar][ah * 16 + 8]) = s1;
        *reinterpret_cast<short8*>(&Bs[tid][0])  = b0;
        *reinterpret_cast<short8*>(&Bs[tid][8])  = b1;
        *reinterpret_cast<short8*>(&Bs[tid][16]) = b2;
        *reinterpret_cast<short8*>(&Bs[tid][24]) = b3;
        __syncthreads();

        short8 af[4], bfr[8];
        #pragma unroll
        for (int mi = 0; mi < 4; ++mi)
            af[mi] = *reinterpret_cast<const short8*>(&As[wm * 64 + mi * 16 + l16][quad * 8]);
        #pragma unroll
        for (int ni = 0; ni < 8; ++ni)
            bfr[ni] = *reinterpret_cast<const short8*>(&Bs[wn * 128 + ni * 16 + l16][quad * 8]);
        #pragma unroll
        for (int mi = 0; mi < 4; ++mi)
            #pragma unroll
            for (int ni = 0; ni < 8; ++ni)
                acc[mi][ni] = __builtin_amdgcn_mfma_f32_16x16x32_bf16(af[mi], bfr[ni], acc[mi][ni], 0, 0, 0);
    }

    #pragma unroll
    for (int mi = 0; mi < 4; ++mi) {
        #pragma unroll
        for (int r = 0; r < 4; ++r) {
            int row = bm + wm * 64 + mi * 16 + quad * 4 + r;
            if (row >= M) continue;
            float* outp = h1 + (size_t)row * NHIDC + wn * 128 + l16;
            #pragma unroll
            for (int ni = 0; ni < 8; ++ni) {
                float v = acc[mi][ni][r];
                v = (v > 0.f) ? v : (expf(v) - 1.f);
                outp[ni * 16] = v;
            }
        }
    }
}

// ---------------- GEMM: C = act(A@B + bias), tile 64x64, KT=16, 256 thr, 4x4 micro ----------------
template<int ACT>
__global__ __launch_bounds__(256)
void gemm_kernel(const float* __restrict__ A, const float* __restrict__ B,
                 const float* __restrict__ bias, float* __restrict__ C,
                 int M, int K, int Ncols)
{
    __shared__ float As[16][68];
    __shared__ float Bs[16][64];
    const int tid = threadIdx.x;
    const int bm = blockIdx.x * 64;
    const int bn = blockIdx.y * 64;
    const int m0 = (tid & 15) * 4;
    const int n0 = (tid >> 4) * 4;
    float acc[4][4] = {};

    const int am = bm + (tid >> 2);
    const int ak = (tid & 3) * 4;
    const int bk = tid >> 4;
    const int bn4 = bn + (tid & 15) * 4;

    for (int kt = 0; kt < K; kt += 16) {
        float4 av;
        if (am < M) av = *reinterpret_cast<const float4*>(A + (size_t)am * K + kt + ak);
        else        av = make_float4(0.f, 0.f, 0.f, 0.f);
        float4 bv = *reinterpret_cast<const float4*>(B + (size_t)(kt + bk) * Ncols + bn4);
        __syncthreads();
        As[ak + 0][tid >> 2] = av.x;
        As[ak + 1][tid >> 2] = av.y;
        As[ak + 2][tid >> 2] = av.z;
        As[ak + 3][tid >> 2] = av.w;
        *reinterpret_cast<float4*>(&Bs[bk][(tid & 15) * 4]) = bv;
        __syncthreads();
        #pragma unroll
        for (int k = 0; k < 16; ++k) {
            float4 a4 = *reinterpret_cast<const float4*>(&As[k][m0]);
            float4 b4 = *reinterpret_cast<const float4*>(&Bs[k][n0]);
            float a_[4] = {a4.x, a4.y, a4.z, a4.w};
            float b_[4] = {b4.x, b4.y, b4.z, b4.w};
            #pragma unroll
            for (int i = 0; i < 4; ++i)
                #pragma unroll
                for (int j = 0; j < 4; ++j)
                    acc[i][j] = fmaf(a_[i], b_[j], acc[i][j]);
        }
    }

    float bvals[4] = {0.f, 0.f, 0.f, 0.f};
    if (bias) {
        bvals[0] = bias[bn + n0 + 0]; bvals[1] = bias[bn + n0 + 1];
        bvals[2] = bias[bn + n0 + 2]; bvals[3] = bias[bn + n0 + 3];
    }
    #pragma unroll
    for (int i = 0; i < 4; ++i) {
        int r = bm + m0 + i;
        if (r >= M) break;
        float v[4];
        #pragma unroll
        for (int j = 0; j < 4; ++j) {
            float t = acc[i][j] + bvals[j];
            if (ACT == 1) t = (t > 0.f) ? t : (expf(t) - 1.f);
            v[j] = t;
        }
        float4 o = make_float4(v[0], v[1], v[2], v[3]);
        *reinterpret_cast<float4*>(C + (size_t)r * Ncols + bn + n0) = o;
    }
}

// ---------------- per-node attention scalars: el, er ----------------
__global__ __launch_bounds__(256)
void attn_kernel(const float* __restrict__ h, const float* __restrict__ attn_l,
                 const float* __restrict__ attn_r, float* __restrict__ el, float* __restrict__ er)
{
    int node = blockIdx.x * 4 + (threadIdx.x >> 6);
    int lane = threadIdx.x & 63;
    if (node >= NN) return;
    float v = h[(size_t)node * 64 + lane];
    float lr = (v > 0.f) ? v : NSLOPE_C * v;
    float a = lr * attn_l[lane];
    float b = lr * attn_r[lane];
    #pragma unroll
    for (int m = 1; m < 64; m <<= 1) {
        a += __shfl_xor(a, m);
        b += __shfl_xor(b, m);
    }
    if (lane == 0) { el[node] = a; er[node] = b; }
}

// ---------------- edge kernel: ew, deg sums, lp partials ----------------
__global__ __launch_bounds__(256)
void edge_kernel(const int* __restrict__ src, const int* __restrict__ dst,
                 const float* __restrict__ wts,
                 const float* __restrict__ h, const float* __restrict__ hl,
                 const float* __restrict__ el, const float* __restrict__ er,
                 const float* __restrict__ s_attn, const float* __restrict__ beta,
                 const float* __restrict__ aw,
                 float* __restrict__ ew, float* __restrict__ deg_s, float* __restrict__ deg_d,
                 float* __restrict__ lp_part)
{
    int tid = blockIdx.x * 256 + threadIdx.x;
    int e = tid >> 4;
    int j = threadIdx.x & 15;
    float lp_p = 0.f, se_p = 0.f, sdf_p = 0.f, sds_p = 0.f;
    int s = 0, d = 0;
    if (e < EE) {
        s = src[e]; d = dst[e];
        const float4 hs = *reinterpret_cast<const float4*>(h  + (size_t)s * 64 + j * 4);
        const float4 hd = *reinterpret_cast<const float4*>(h  + (size_t)d * 64 + j * 4);
        const float4 ls = *reinterpret_cast<const float4*>(hl + (size_t)s * 64 + j * 4);
        const float4 ld = *reinterpret_cast<const float4*>(hl + (size_t)d * 64 + j * 4);
        const float4 sa = *reinterpret_cast<const float4*>(s_attn + j * 4);
        se_p = ls.x * sa.x * ld.x + ls.y * sa.y * ld.y + ls.z * sa.z * ld.z + ls.w * sa.w * ld.w;
        float dx = hs.x - hd.x, dy = hs.y - hd.y, dz = hs.z - hd.z, dw = hs.w - hd.w;
        sdf_p = dx * dx + dy * dy + dz * dz + dw * dw;
        float ex = ls.x - ld.x, ey = ls.y - ld.y, ez = ls.z - ld.z, ec = ls.w - ld.w;
        sds_p = ex * ex + ey * ey + ez * ez + ec * ec;
        float dot = ls.x * ld.x + ls.y * ld.y + ls.z * ld.z + ls.w * ld.w;
        lp_p = dot * wts[e];
    }
    #pragma unroll
    for (int m = 1; m < 16; m <<= 1) {
        se_p  += __shfl_xor(se_p, m);
        sdf_p += __shfl_xor(sdf_p, m);
        sds_p += __shfl_xor(sds_p, m);
    }
    if (e < EE && j == 0) {
        float betaw = 2.f / (expf(-beta[0]) + 1.f);
        float a0 = aw[0], a1 = aw[1];
        float mx = fmaxf(a0, a1);
        float e0 = expf(a0 - mx), e1 = expf(a1 - mx);
        float inv = 1.f / (e0 + e1);
        float w0 = e0 * inv, w1 = e1 * inv;
        float evv = el[s] + er[d] + se_p;
        float dd = w0 * sdf_p + w1 * sds_p;
        float v = expf(evv - betaw * dd) + 1e-9f;
        ew[e] = v;
        atomicAdd(deg_s + s, v);
        atomicAdd(deg_d + d, v);
    }
    #pragma unroll
    for (int m = 1; m < 64; m <<= 1) lp_p += __shfl_xor(lp_p, m);
    __shared__ float lred[4];
    if ((threadIdx.x & 63) == 0) lred[threadIdx.x >> 6] = lp_p;
    __syncthreads();
    if (threadIdx.x == 0) lp_part[blockIdx.x] = lred[0] + lred[1] + lred[2] + lred[3];
}

// ---------------- reduce lp partials ----------------
__global__ __launch_bounds__(256)
void reduce_kernel(const float* __restrict__ part, int n, float* __restrict__ out)
{
    float s = 0.f;
    for (int i = threadIdx.x; i < n; i += 256) s += part[i];
    #pragma unroll
    for (int m = 1; m < 64; m <<= 1) s += __shfl_xor(s, m);
    __shared__ float sd[4];
    if ((threadIdx.x & 63) == 0) sd[threadIdx.x >> 6] = s;
    __syncthreads();
    if (threadIdx.x == 0) out[0] = sd[0] + sd[1] + sd[2] + sd[3];
}

// ---------------- edge normalization ----------------
__global__ __launch_bounds__(256)
void wnorm_kernel(const int* __restrict__ src, const int* __restrict__ dst,
                  const float* __restrict__ deg_s, const float* __restrict__ deg_d,
                  const float* __restrict__ theta, float* __restrict__ ew)
{
    int e = blockIdx.x * 256 + threadIdx.x;
    if (e >= EE) return;
    float perm = 1e-9f / (expf(-theta[0]) + 1.f);
    float v = ew[e] * rsqrtf(deg_s[src[e]]) * rsqrtf(deg_d[dst[e]]) + perm;
    ew[e] = v;
}

// ---------------- CSR build ----------------
__global__ __launch_bounds__(256)
void count_kernel(const int* __restrict__ dst, int* __restrict__ cnt)
{
    int e = blockIdx.x * 256 + threadIdx.x;
    if (e < EE) atomicAdd(cnt + dst[e], 1);
}

__global__ __launch_bounds__(1024)
void scan_kernel(const int* __restrict__ cnt, int* __restrict__ row, int* __restrict__ cur)
{
    __shared__ int sums[1024];
    int t = threadIdx.x;
    const int CH = (NN + 1023) / 1024;
    int lo = t * CH, hi = min(lo + CH, NN);
    int s = 0;
    for (int i = lo; i < hi; ++i) s += cnt[i];
    sums[t] = s;
    __syncthreads();
    for (int off = 1; off < 1024; off <<= 1) {
        int add = (t >= off) ? sums[t - off] : 0;
        __syncthreads();
        sums[t] += add;
        __syncthreads();
    }
    int running = sums[t] - s;
    for (int i = lo; i < hi; ++i) {
        row[i] = running;
        cur[i] = running;
        running += cnt[i];
    }
    if (t == 1023) row[NN] = sums[1023];
}

__global__ __launch_bounds__(256)
void bucket_kernel(const int* __restrict__ src, const int* __restrict__ dst,
                   const float* __restrict__ w, int* __restrict__ cur,
                   int* __restrict__ csr_src, float* __restrict__ csr_w)
{
    int e = blockIdx.x * 256 + threadIdx.x;
    if (e >= EE) return;
    int d = dst[e];
    int pos = atomicAdd(cur + d, 1);
    csr_src[pos] = src[e];
    csr_w[pos] = (1.0f - ALPHA_C) * w[e];
}

// ---------------- propagation (bf16 gather, fp32 accumulate) ----------------
// fin is bf16 [NN][64]. Lane f (0..15) loads 4 bf16 (8 B); sub = 4 edges in flight.
// OUTBF=1: store bf16 (next iteration's gather source); OUTBF=0: store fp32 (final).
template<int OUTBF>
__global__ __launch_bounds__(256)
void prop_kernel(const short* __restrict__ fin, const float* __restrict__ h,
                 const int* __restrict__ row, const int* __restrict__ csr_src,
                 const float* __restrict__ csr_w,
                 short* __restrict__ foutb, float* __restrict__ foutf)
{
    int node = blockIdx.x * 4 + (threadIdx.x >> 6);
    int lane = threadIdx.x & 63;
    int sub = lane >> 4;
    int f = lane & 15;
    if (node >= NN) return;
    int b = row[node], en = row[node + 1];
    float4 acc = make_float4(0.f, 0.f, 0.f, 0.f);
    for (int e = b + sub; e < en; e += 4) {
        int s = csr_src[e];
        float wv = csr_w[e];
        short4v v = *reinterpret_cast<const short4v*>(fin + (size_t)s * 64 + f * 4);
        acc.x = fmaf(wv, bf2f(v[0]), acc.x);
        acc.y = fmaf(wv, bf2f(v[1]), acc.y);
        acc.z = fmaf(wv, bf2f(v[2]), acc.z);
        acc.w = fmaf(wv, bf2f(v[3]), acc.w);
    }
    #pragma unroll
    for (int m = 16; m < 64; m <<= 1) {
        acc.x += __shfl_xor(acc.x, m);
        acc.y += __shfl_xor(acc.y, m);
        acc.z += __shfl_xor(acc.z, m);
        acc.w += __shfl_xor(acc.w, m);
    }
    if (sub == 0) {
        const float4 hv = *reinterpret_cast<const float4*>(h + (size_t)node * 64 + f * 4);
        float ox = fmaf(ALPHA_C, hv.x, acc.x);
        float oy = fmaf(ALPHA_C, hv.y, acc.y);
        float oz = fmaf(ALPHA_C, hv.z, acc.z);
        float ow = fmaf(ALPHA_C, hv.w, acc.w);
        if (OUTBF) {
            short4v o;
            o[0] = f2bf(ox); o[1] = f2bf(oy); o[2] = f2bf(oz); o[3] = f2bf(ow);
            *reinterpret_cast<short4v*>(foutb + (size_t)node * 64 + f * 4) = o;
        } else {
            *reinterpret_cast<float4*>(foutf + (size_t)node * 64 + f * 4) =
                make_float4(ox, oy, oz, ow);
        }
    }
}

// ---------------- epilogue: out = log_softmax(elu(fp)) ----------------
__global__ __launch_bounds__(256)
void out_kernel(const float* __restrict__ fp, float* __restrict__ out)
{
    int node = blockIdx.x * 4 + (threadIdx.x >> 6);
    int lane = threadIdx.x & 63;
    if (node >= NN) return;
    float v = fp[(size_t)node * 64 + lane];
    float ev = (v > 0.f) ? v : (expf(v) - 1.f);
    float m = ev;
    #pragma unroll
    for (int k = 1; k < 64; k <<= 1) m = fmaxf(m, __shfl_xor(m, k));
    float s = expf(ev - m);
    #pragma unroll
    for (int k = 1; k < 64; k <<= 1) s += __shfl_xor(s, k);
    out[(size_t)node * 64 + lane] = ev - m - logf(s);
}

extern "C" void kernel_launch(void* const* d_in, const int* in_sizes, int n_in,
                              void* d_out, int out_size, void* d_ws, size_t ws_size,
                              hipStream_t stream)
{
    const float* x      = (const float*)d_in[0];
    const int*   src    = (const int*)d_in[1];
    const int*   dst    = (const int*)d_in[2];
    const float* wts    = (const float*)d_in[3];
    const float* latp   = (const float*)d_in[4];
    const float* W_in   = (const float*)d_in[5];
    const float* W_out  = (const float*)d_in[6];
    const float* Ws1    = (const float*)d_in[7];
    const float* b1     = (const float*)d_in[8];
    const float* Ws2    = (const float*)d_in[9];
    const float* b2     = (const float*)d_in[10];
    const float* attn_l = (const float*)d_in[11];
    const float* attn_r = (const float*)d_in[12];
    const float* s_attn = (const float*)d_in[13];
    const float* beta   = (const float*)d_in[14];
    const float* theta  = (const float*)d_in[15];
    const float* aw     = (const float*)d_in[16];

    float* out = (float*)d_out;
    float* lp  = out + (size_t)NN * 64;

    char* w8 = (char*)d_ws;
    size_t off = 0;
    auto alloc = [&](size_t bytes) -> char* {
        char* p = w8 + off;
        off += (bytes + 255) / 256 * 256;
        return p;
    };
    // big region (NN*256 fp32 = 102.4 MB): h1 during gemm1->gemm2; afterwards
    // reused for hl_tmp, then for h_bf / fpA_bf / fpB_bf / fpF (12.8+12.8+12.8+25.6 MB).
    float* big    = (float*)alloc((size_t)NN * 256 * 4);
    float* h1     = big;
    float* hl_tmp = big;
    short* h_bf   = (short*)big;
    short* fpA_bf = (short*)big + (size_t)NN * 64;
    short* fpB_bf = (short*)big + (size_t)NN * 64 * 2;
    float* fpF    = (float*)((short*)big + (size_t)NN * 64 * 3);
    float* h      = (float*)alloc((size_t)NN * 64 * 4);
    float* hl     = (float*)alloc((size_t)NN * 64 * 4);
    float* ew     = (float*)alloc((size_t)EE * 4);
    float* el     = (float*)alloc((size_t)NN * 4);
    float* er     = (float*)alloc((size_t)NN * 4);
    float* deg_s  = (float*)alloc((size_t)NN * 4);
    float* deg_d  = (float*)alloc((size_t)NN * 4);
    int*   cnt    = (int*)alloc((size_t)NN * 4);
    int*   row    = (int*)alloc((size_t)(NN + 1) * 4);
    int*   cur    = (int*)alloc((size_t)NN * 4);
    int*   csr_src= (int*)alloc((size_t)EE * 4);
    float* csr_w  = (float*)alloc((size_t)EE * 4);
    float* lp_part= (float*)alloc((size_t)100000 * 4);
    short* WT     = (short*)alloc((size_t)NHIDC * NFEATC * 2);

    hipMemsetAsync(cnt,   0, (size_t)NN * 4, stream);
    hipMemsetAsync(deg_s, 0, (size_t)NN * 4, stream);
    hipMemsetAsync(deg_d, 0, (size_t)NN * 4, stream);

    const int MB = (NN + 63) / 64;  // 1563

    // h1 = elu(x @ W_in)  -- bf16 MFMA path
    castWT_kernel<<<NFEATC, 256, 0, stream>>>(W_in, WT, NFEATC, NHIDC);
    gemm1_mfma_kernel<<<(NN + 127) / 128, 256, 0, stream>>>(x, WT, h1, NN);

    gemm_kernel<0><<<dim3(MB, 1), 256, 0, stream>>>(h1, W_out, nullptr, h, NN, NHIDC, NCC);
    gemm_kernel<1><<<dim3(MB, 1), 256, 0, stream>>>(latp, Ws1, b1, hl_tmp, NN, NCC, NCC);
    gemm_kernel<1><<<dim3(MB, 1), 256, 0, stream>>>(hl_tmp, Ws2, b2, hl, NN, NCC, NCC);
    // note: hl_tmp aliases big; h_bf cast happens after hl is done with big.

    attn_kernel<<<NN / 4, 256, 0, stream>>>(h, attn_l, attn_r, el, er);
    count_kernel<<<EE / 256, 256, 0, stream>>>(dst, cnt);
    scan_kernel<<<1, 1024, 0, stream>>>(cnt, row, cur);

    edge_kernel<<<EE * 16 / 256, 256, 0, stream>>>(src, dst, wts, h, hl, el, er,
                                                   s_attn, beta, aw, ew, deg_s, deg_d, lp_part);
    reduce_kernel<<<1, 256, 0, stream>>>(lp_part, EE * 16 / 256 > 100000 ? 100000 : EE * 16 / 256, lp);

    wnorm_kernel<<<EE / 256, 256, 0, stream>>>(src, dst, deg_s, deg_d, theta, ew);
    bucket_kernel<<<EE / 256, 256, 0, stream>>>(src, dst, ew, cur, csr_src, csr_w);

    // cast h -> bf16 gather source
    cast_bf_kernel<<<(NN * 64 / 4 + 255) / 256, 256, 0, stream>>>(h, h_bf, NN * 64 / 4);

    const short* fin = h_bf;
    short* bufs[2] = {fpA_bf, fpB_bf};
    for (int it = 0; it < 7; ++it) {
        short* fo = bufs[it & 1];
        prop_kernel<1><<<NN / 4, 256, 0, stream>>>(fin, h, row, csr_src, csr_w, fo, nullptr);
        fin = fo;
    }
    prop_kernel<0><<<NN / 4, 256, 0, stream>>>(fin, h, row, csr_src, csr_w, nullptr, fpF);
    out_kernel<<<NN / 4, 256, 0, stream>>>(fpF, out);
}